// Round 8
// baseline (3794.207 us; speedup 1.0000x reference)
//
#include <hip/hip_runtime.h>
#include <math.h>

typedef __attribute__((ext_vector_type(8))) short short8;
typedef __attribute__((ext_vector_type(4))) float floatx4;
typedef __attribute__((ext_vector_type(4))) unsigned uintx4;

#define NB 256
#define NH 512
#define NXP 256
#define NT 512
#define GH2 200   // padded f32 row stride for gh/gx LDS (192 cols + pad)

#define MFMA __builtin_amdgcn_mfma_f32_16x16x32_bf16

__device__ __forceinline__ unsigned short f2bf(float f) {
    union { float f; unsigned u; } x; x.f = f;
    unsigned r = x.u + 0x7FFFu + ((x.u >> 16) & 1u);
    return (unsigned short)(r >> 16);
}
__device__ __forceinline__ float sigmoidf_(float x) { return 1.0f / (1.0f + __expf(-x)); }

__device__ __forceinline__ short8 cvt8(float4 u, float4 v) {
    short8 r;
    r[0] = (short)f2bf(u.x); r[1] = (short)f2bf(u.y);
    r[2] = (short)f2bf(u.z); r[3] = (short)f2bf(u.w);
    r[4] = (short)f2bf(v.x); r[5] = (short)f2bf(v.y);
    r[6] = (short)f2bf(v.z); r[7] = (short)f2bf(v.w);
    return r;
}

// ---- device-coherent data ops (sc0 sc1) — PROVEN cross-XCD (r3/r5/r7).
//      sc0-only path REFUTED (r6 stale reads) — do not revisit.
__device__ __forceinline__ void ldg2_c(const void* p0, const void* p1,
                                       uintx4& r0, uintx4& r1) {
    asm volatile(
        "global_load_dwordx4 %0, %2, off sc0 sc1\n\t"
        "global_load_dwordx4 %1, %3, off sc0 sc1\n\t"
        "s_waitcnt vmcnt(0)"
        : "=&v"(r0), "=&v"(r1) : "v"(p0), "v"(p1) : "memory");
}
__device__ __forceinline__ void ldg1_c(const void* p0, uintx4& r0) {
    asm volatile(
        "global_load_dwordx4 %0, %1, off sc0 sc1\n\t"
        "s_waitcnt vmcnt(0)"
        : "=&v"(r0) : "v"(p0) : "memory");
}
__device__ __forceinline__ void st16_c(void* p, unsigned v) {
    asm volatile("global_store_short %0, %1, off sc0 sc1" :: "v"(p), "v"(v) : "memory");
}
__device__ __forceinline__ void st32_c(void* p, unsigned v) {
    asm volatile("global_store_dword %0, %1, off sc0 sc1" :: "v"(p), "v"(v) : "memory");
}
__device__ __forceinline__ void vm_drain() {
    asm volatile("s_waitcnt vmcnt(0)" ::: "memory");
}

// ---- flag fabric: relaxed agent atomics (proven), single writer,
//      one flag per 64B line: flag i at f[i*16]. ----
__device__ __forceinline__ void flag_set(int* f, int v) {
    __hip_atomic_store(f, v, __ATOMIC_RELAXED, __HIP_MEMORY_SCOPE_AGENT);
}
// wave-0-only pollers
__device__ __forceinline__ void poll64(const int* f, int target, int lane) {
    const int* fp = f + lane * 16;
    for (;;) {
        int v = __hip_atomic_load(fp, __ATOMIC_RELAXED, __HIP_MEMORY_SCOPE_AGENT);
        if (__ballot(v < target) == 0ull) break;
        __builtin_amdgcn_s_sleep(1);
    }
}
__device__ __forceinline__ void poll16(const int* f, int target, int lane) {
    const int* fp = f + (lane & 15) * 16;
    for (;;) {
        int v = __hip_atomic_load(fp, __ATOMIC_RELAXED, __HIP_MEMORY_SCOPE_AGENT);
        if (__ballot(v < target) == 0ull) break;
        __builtin_amdgcn_s_sleep(1);
    }
}

__global__ void k_cvt(const float* __restrict__ src, unsigned short* __restrict__ dst, int n) {
    int i = blockIdx.x * blockDim.x + threadIdx.x;
    int stride = gridDim.x * blockDim.x;
    for (; i < n; i += stride) dst[i] = f2bf(src[i]);
}

struct KParams {
    const float *xl, *xt, *xw, *xs;
    const float *bih, *bhh, *bt;
    const unsigned short *Wihb, *Whhb, *Wthb, *Wtxb;
    unsigned short *hb0, *hb1, *xpb;
    float *out;
    int *flags;
};

// 128 blocks x 512 threads. group = 8 blocks sharing batch rows m0..m0+15.
// block jc owns h-cols j0..j0+63 (gates) and x'-cols n0..n0+31.
__global__ __launch_bounds__(512, 2)
void k_persist(KParams P)
{
    const int tid   = threadIdx.x;
    const int w     = tid >> 6;          // 0..7
    const int lane  = tid & 63;
    const int lr    = lane & 15;
    const int lkrow = lane >> 4;
    const int lk    = lkrow * 8;
    const int bid   = blockIdx.x;
    const int grp   = bid >> 3;          // 0..15
    const int jc    = bid & 7;           // 0..7
    const int m0    = grp * 16;
    const int j0    = jc * 64;
    const int n0    = jc * 32;

    // per-group flag region: 2048 ints (8 KB)
    //   hfl: 64 flags (8 blocks x 8 waves) at [i*16]
    //   xfl: 16 flags (8 blocks x 2 x'-waves) at [1024 + i*16]
    int* gfl = P.flags + grp * 2048;
    int* hfl = gfl;
    int* xfl = gfl + 1024;

    __shared__ unsigned short sh_h[16 * 512];
    __shared__ unsigned short sh_xp[16 * 256];
    __shared__ float sh_gh[16 * GH2];
    __shared__ float sh_gx[2][16 * GH2];
    __shared__ float sh_hf[16 * 64];
    __shared__ float sh_b[6][64];
    __shared__ float sh_bt[32];

    if (tid < 64) {
        sh_b[0][tid] = P.bih[j0 + tid];
        sh_b[1][tid] = P.bih[512 + j0 + tid];
        sh_b[2][tid] = P.bih[1024 + j0 + tid];
        sh_b[3][tid] = P.bhh[j0 + tid];
        sh_b[4][tid] = P.bhh[512 + j0 + tid];
        sh_b[5][tid] = P.bhh[1024 + j0 + tid];
    }
    if (tid < 32) sh_bt[tid] = P.bt[n0 + tid];
    sh_hf[tid] = 0.f; sh_hf[tid + 512] = 0.f;

    // ---- hoist step-invariant MFMA B-operands into registers ----
    short8 bWih[3][4];   // Phase B: unit u = w*3+i -> tile=u>>1 (g=tile>>2, sub=tile&3), kh=u&1
    short8 bW[2][16];    // Phase A: w<6 -> Whh (gate g=w>>1, colpair cp=w&1, sub 0/1)
                         //          w>=6 -> [0]=Wth (16 frags), [1][0..4]=Wtx
    #pragma unroll
    for (int i = 0; i < 3; ++i) {
        const int u = w * 3 + i, tile = u >> 1, kh = u & 1;
        const int g = tile >> 2, sub = tile & 3;
        const unsigned short* bp =
            P.Wihb + (size_t)(g * 512 + j0 + sub * 16 + lr) * NXP + kh * 128 + lk;
        #pragma unroll
        for (int kb = 0; kb < 4; ++kb) bWih[i][kb] = *(const short8*)(bp + kb * 32);
    }
    if (w < 6) {
        const int g = w >> 1, cp = w & 1;
        #pragma unroll
        for (int sub = 0; sub < 2; ++sub) {
            const unsigned short* bp =
                P.Whhb + (size_t)(g * 512 + j0 + cp * 32 + sub * 16 + lr) * NH + lk;
            #pragma unroll
            for (int kb = 0; kb < 16; ++kb) bW[sub][kb] = *(const short8*)(bp + kb * 32);
        }
    } else {
        const int n = n0 + (w - 6) * 16;
        const unsigned short* bp = P.Wthb + (size_t)(n + lr) * NH + lk;
        #pragma unroll
        for (int kb = 0; kb < 16; ++kb) bW[0][kb] = *(const short8*)(bp + kb * 32);
        const unsigned short* bx = P.Wtxb + (size_t)(n + lr) * 160 + lk;
        #pragma unroll
        for (int c = 0; c < 5; ++c) bW[1][c] = *(const short8*)(bx + c * 32);
    }
    __syncthreads();

    for (int t = 0; t < NT; ++t) {
        const unsigned short* hsrc = (t & 1) ? P.hb1 : P.hb0;
        unsigned short*       hdst = (t & 1) ? P.hb0 : P.hb1;

        // x-input loads early (plain cached; overlap the h-poll)
        float4 xq[5][2];
        if (w >= 6) {
            const size_t r = (size_t)(m0 + lr);
            #pragma unroll
            for (int c = 0; c < 5; ++c) {
                const float* pa = (c < 2) ? P.xl + (r * NT + t) * 64 + c * 32 + lk
                                : (c == 2)? P.xt + (r * NT + t) * 32 + lk
                                : (c == 3)? P.xw + (r * NT + t) * 32 + lk
                                          : P.xs + (r * NT + t) * 32 + lk;
                xq[c][0] = *(const float4*)pa;
                xq[c][1] = *(const float4*)(pa + 4);
            }
        }

        // ---- wait for h_t (64 per-wave flags), single-wave poll ----
        if (w == 0) poll64(hfl, t, lane);
        __syncthreads();
        // stage h[16 x 512] -> LDS (32 B/thread)
        {
            const int row = tid >> 5, c = (tid & 31) * 16;
            const unsigned short* gp = hsrc + (size_t)(m0 + row) * NH + c;
            uintx4 r0, r1;
            ldg2_c(gp, gp + 8, r0, r1);
            const int sw = (row & 7) * 8;
            *(uintx4*)&sh_h[row * 512 + ((c + 0) ^ sw)] = r0;
            *(uintx4*)&sh_h[row * 512 + ((c + 8) ^ sw)] = r1;
        }
        __syncthreads();

        // ---- Phase A: gh (waves 0-5) / x' (waves 6-7) ----
        if (w < 6) {
            const int g = w >> 1, cp = w & 1;
            floatx4 a0 = (floatx4){0.f,0.f,0.f,0.f};
            floatx4 a1 = (floatx4){0.f,0.f,0.f,0.f};
            const int sw = (lr & 7) * 8;
            #pragma unroll
            for (int kb = 0; kb < 16; ++kb) {
                short8 a = *(const short8*)&sh_h[lr * 512 + ((kb * 32 + lk) ^ sw)];
                a0 = MFMA(a, bW[0][kb], a0, 0, 0, 0);
                a1 = MFMA(a, bW[1][kb], a1, 0, 0, 0);
            }
            #pragma unroll
            for (int rg = 0; rg < 4; ++rg) {
                const int row = lkrow * 4 + rg;
                sh_gh[row * GH2 + g * 64 + cp * 32 + lr]      = a0[rg];
                sh_gh[row * GH2 + g * 64 + cp * 32 + 16 + lr] = a1[rg];
            }
        } else {
            floatx4 acc = (floatx4){0.f,0.f,0.f,0.f};
            const int sw = (lr & 7) * 8;
            #pragma unroll
            for (int kb = 0; kb < 16; ++kb) {
                short8 a = *(const short8*)&sh_h[lr * 512 + ((kb * 32 + lk) ^ sw)];
                acc = MFMA(a, bW[0][kb], acc, 0, 0, 0);
            }
            #pragma unroll
            for (int c = 0; c < 5; ++c) {
                short8 a = cvt8(xq[c][0], xq[c][1]);
                acc = MFMA(a, bW[1][c], acc, 0, 0, 0);
            }
            const int xcol = n0 + (w - 6) * 16 + lr;
            #pragma unroll
            for (int rg = 0; rg < 4; ++rg) {
                const int row = lkrow * 4 + rg;
                unsigned short v = f2bf(tanhf(acc[rg] + sh_bt[(w - 6) * 16 + lr]));
                st16_c(P.xpb + (size_t)(m0 + row) * NXP + xcol, (unsigned)v);
            }
            vm_drain();
            if (lane == 0) flag_set(xfl + (jc * 2 + (w - 6)) * 16, t + 1);
        }

        // ---- wait for x'_t (16 flags), single-wave poll ----
        if (w == 0) poll16(xfl, t + 1, lane);
        __syncthreads();
        // stage x'[16 x 256] -> LDS (16 B/thread)
        {
            const int row = tid >> 5, c = (tid & 31) * 8;
            const unsigned short* gp = P.xpb + (size_t)(m0 + row) * NXP + c;
            uintx4 r0;
            ldg1_c(gp, r0);
            const int sw = (row & 7) * 8;
            *(uintx4*)&sh_xp[row * 256 + (c ^ sw)] = r0;
        }
        __syncthreads();

        // ---- Phase B: gx (24 K-split units over 8 waves) ----
        #pragma unroll
        for (int i = 0; i < 3; ++i) {
            const int u = w * 3 + i, tile = u >> 1, kh = u & 1;
            const int g = tile >> 2, sub = tile & 3;
            floatx4 acc = (floatx4){0.f,0.f,0.f,0.f};
            const int sw = (lr & 7) * 8;
            #pragma unroll
            for (int kb = 0; kb < 4; ++kb) {
                short8 a = *(const short8*)&sh_xp[lr * 256 + ((kh * 128 + kb * 32 + lk) ^ sw)];
                acc = MFMA(a, bWih[i][kb], acc, 0, 0, 0);
            }
            #pragma unroll
            for (int rg = 0; rg < 4; ++rg) {
                const int row = lkrow * 4 + rg;
                sh_gx[kh][row * GH2 + g * 64 + sub * 16 + lr] = acc[rg];
            }
        }
        __syncthreads();

        // ---- epilogue: gates + h update (2 adjacent cols/thread) ----
        {
            const int row = tid >> 5, jl = (tid & 31) * 2;
            float hn[2];
            #pragma unroll
            for (int jo = 0; jo < 2; ++jo) {
                const int j = jl + jo;
                float gxr = sh_gx[0][row * GH2 + j]       + sh_gx[1][row * GH2 + j];
                float gxz = sh_gx[0][row * GH2 + 64 + j]  + sh_gx[1][row * GH2 + 64 + j];
                float gxn = sh_gx[0][row * GH2 + 128 + j] + sh_gx[1][row * GH2 + 128 + j];
                float ghr = sh_gh[row * GH2 + j];
                float ghz = sh_gh[row * GH2 + 64 + j];
                float ghn = sh_gh[row * GH2 + 128 + j];
                float rg_ = sigmoidf_(gxr + ghr + sh_b[0][j] + sh_b[3][j]);
                float zg  = sigmoidf_(gxz + ghz + sh_b[1][j] + sh_b[4][j]);
                float ng  = tanhf(gxn + sh_b[2][j] + rg_ * (ghn + sh_b[5][j]));
                float hold = sh_hf[row * 64 + j];
                hn[jo] = (1.f - zg) * ng + zg * hold;
                sh_hf[row * 64 + j] = hn[jo];
            }
            unsigned d = (unsigned)f2bf(hn[0]) | ((unsigned)f2bf(hn[1]) << 16);
            st32_c(hdst + (size_t)(m0 + row) * NH + j0 + jl, d);
            if (t == NT - 1) {
                float2 o; o.x = hn[0]; o.y = hn[1];
                *(float2*)&P.out[(size_t)(m0 + row) * NH + j0 + jl] = o;
            }
            vm_drain();
            // per-wave h flag: wave w covers rows 2w, 2w+1; signal right after drain
            if (lane == 0) flag_set(hfl + (jc * 8 + w) * 16, t + 1);
        }
    }
}

extern "C" void kernel_launch(void* const* d_in, const int* in_sizes, int n_in,
                              void* d_out, int out_size, void* d_ws, size_t ws_size,
                              hipStream_t stream)
{
    (void)in_sizes; (void)n_in; (void)out_size;
    const float* xl  = (const float*)d_in[0];
    const float* xt_ = (const float*)d_in[1];
    const float* xw  = (const float*)d_in[2];
    const float* xs  = (const float*)d_in[3];
    const float* Wih = (const float*)d_in[4];
    const float* Whh = (const float*)d_in[5];
    const float* bih = (const float*)d_in[6];
    const float* bhh = (const float*)d_in[7];
    const float* Wth = (const float*)d_in[8];
    const float* Wtx = (const float*)d_in[9];
    const float* bt  = (const float*)d_in[10];

    char* p = (char*)d_ws;
    int* flags = (int*)p;                       p += 16 * 2048 * 4;   // 131072 B
    unsigned short* hb0 = (unsigned short*)p;   p += (size_t)NB * NH * 2;
    unsigned short* hb1 = (unsigned short*)p;   p += (size_t)NB * NH * 2;
    unsigned short* xpb = (unsigned short*)p;   p += (size_t)NB * NXP * 2;
    unsigned short* Wihb = (unsigned short*)p;  p += (size_t)1536 * 256 * 2;
    unsigned short* Whhb = (unsigned short*)p;  p += (size_t)1536 * 512 * 2;
    unsigned short* Wthb = (unsigned short*)p;  p += (size_t)256 * 512 * 2;
    unsigned short* Wtxb = (unsigned short*)p;  p += (size_t)256 * 160 * 2;
    if ((size_t)(p - (char*)d_ws) > ws_size) return;

    k_cvt<<<256, 256, 0, stream>>>(Wih, Wihb, 1536 * 256);
    k_cvt<<<256, 256, 0, stream>>>(Whh, Whhb, 1536 * 512);
    k_cvt<<<64, 256, 0, stream>>>(Wth, Wthb, 256 * 512);
    k_cvt<<<32, 256, 0, stream>>>(Wtx, Wtxb, 256 * 160);
    hipMemsetAsync(flags, 0, 16 * 2048 * 4, stream);
    hipMemsetAsync(hb0, 0, (size_t)NB * NH * 2, stream);

    KParams P;
    P.xl = xl; P.xt = xt_; P.xw = xw; P.xs = xs;
    P.bih = bih; P.bhh = bhh; P.bt = bt;
    P.Wihb = Wihb; P.Whhb = Whhb; P.Wthb = Wthb; P.Wtxb = Wtxb;
    P.hb0 = hb0; P.hb1 = hb1; P.xpb = xpb;
    P.out = (float*)d_out; P.flags = flags;

    void* args[] = { &P };
    if (hipLaunchCooperativeKernel((const void*)k_persist, dim3(128), dim3(512),
                                   args, 0, stream) != hipSuccess) {
        k_persist<<<128, 512, 0, stream>>>(P);
    }
}

// Round 9
// 3371.323 us; speedup vs baseline: 1.1254x; 1.1254x over previous
//
#include <hip/hip_runtime.h>
#include <math.h>

typedef __attribute__((ext_vector_type(8))) short short8;
typedef __attribute__((ext_vector_type(4))) float floatx4;
typedef __attribute__((ext_vector_type(4))) unsigned uintx4;

#define NB 256
#define NH 512
#define NXP 256
#define NT 512
#define GHP 100

#define MFMA __builtin_amdgcn_mfma_f32_16x16x32_bf16

__device__ __forceinline__ unsigned short f2bf(float f) {
    union { float f; unsigned u; } x; x.f = f;
    unsigned r = x.u + 0x7FFFu + ((x.u >> 16) & 1u);
    return (unsigned short)(r >> 16);
}
__device__ __forceinline__ float sigmoidf_(float x) { return 1.0f / (1.0f + __expf(-x)); }

__device__ __forceinline__ short8 cvt8(float4 u, float4 v) {
    short8 r;
    r[0] = (short)f2bf(u.x); r[1] = (short)f2bf(u.y);
    r[2] = (short)f2bf(u.z); r[3] = (short)f2bf(u.w);
    r[4] = (short)f2bf(v.x); r[5] = (short)f2bf(v.y);
    r[6] = (short)f2bf(v.z); r[7] = (short)f2bf(v.w);
    return r;
}

// ---- device-coherent data ops (sc0 sc1) — PROVEN cross-XCD (r3/r5/r7).
//      sc0-only path REFUTED (r6 stale reads) — do not revisit.
__device__ __forceinline__ void ldg4_c(const void* p0, const void* p1,
                                       const void* p2, const void* p3,
                                       uintx4& r0, uintx4& r1, uintx4& r2, uintx4& r3) {
    asm volatile(
        "global_load_dwordx4 %0, %4, off sc0 sc1\n\t"
        "global_load_dwordx4 %1, %5, off sc0 sc1\n\t"
        "global_load_dwordx4 %2, %6, off sc0 sc1\n\t"
        "global_load_dwordx4 %3, %7, off sc0 sc1\n\t"
        "s_waitcnt vmcnt(0)"
        : "=&v"(r0), "=&v"(r1), "=&v"(r2), "=&v"(r3)
        : "v"(p0), "v"(p1), "v"(p2), "v"(p3) : "memory");
}
__device__ __forceinline__ void ldg2_c(const void* p0, const void* p1,
                                       uintx4& r0, uintx4& r1) {
    asm volatile(
        "global_load_dwordx4 %0, %2, off sc0 sc1\n\t"
        "global_load_dwordx4 %1, %3, off sc0 sc1\n\t"
        "s_waitcnt vmcnt(0)"
        : "=&v"(r0), "=&v"(r1) : "v"(p0), "v"(p1) : "memory");
}
__device__ __forceinline__ void st16_c(void* p, unsigned v) {
    asm volatile("global_store_short %0, %1, off sc0 sc1" :: "v"(p), "v"(v) : "memory");
}
__device__ __forceinline__ void st32_c(void* p, unsigned v) {
    asm volatile("global_store_dword %0, %1, off sc0 sc1" :: "v"(p), "v"(v) : "memory");
}
__device__ __forceinline__ void vm_drain() {
    asm volatile("s_waitcnt vmcnt(0)" ::: "memory");
}

// ---- flag fabric: relaxed agent atomics (proven), single writer,
//      one flag per 64B line: flag i at f[i*16]. ----
__device__ __forceinline__ void flag_set(int* f, int v) {
    __hip_atomic_store(f, v, __ATOMIC_RELAXED, __HIP_MEMORY_SCOPE_AGENT);
}
__device__ __forceinline__ void poll64(const int* f, int target, int lane) {
    const int* fp = f + lane * 16;
    for (;;) {
        int v = __hip_atomic_load(fp, __ATOMIC_RELAXED, __HIP_MEMORY_SCOPE_AGENT);
        if (__ballot(v < target) == 0ull) break;
        __builtin_amdgcn_s_sleep(1);
    }
}
__device__ __forceinline__ void poll16(const int* f, int target, int lane) {
    const int* fp = f + (lane & 15) * 16;
    for (;;) {
        int v = __hip_atomic_load(fp, __ATOMIC_RELAXED, __HIP_MEMORY_SCOPE_AGENT);
        if (__ballot(v < target) == 0ull) break;
        __builtin_amdgcn_s_sleep(1);
    }
}

__global__ void k_cvt(const float* __restrict__ src, unsigned short* __restrict__ dst, int n) {
    int i = blockIdx.x * blockDim.x + threadIdx.x;
    int stride = gridDim.x * blockDim.x;
    for (; i < n; i += stride) dst[i] = f2bf(src[i]);
}

struct KParams {
    const float *xl, *xt, *xw, *xs;
    const float *bih, *bhh, *bt;
    const unsigned short *Wihb, *Whhb, *Wthb, *Wtxb;
    unsigned short *hb0, *hb1, *xpb;
    float *out;
    int *flags;
};

// 256 blocks x 256 threads (4 waves). group = 16 blocks sharing rows m0..m0+15.
// block jc owns h-cols j0..j0+31 (gates) and x'-cols n0..n0+15.
__global__ __launch_bounds__(256, 1)
void k_persist(KParams P)
{
    const int tid   = threadIdx.x;
    const int w     = tid >> 6;
    const int lane  = tid & 63;
    const int lr    = lane & 15;
    const int lkrow = lane >> 4;
    const int lk    = lkrow * 8;
    const int bid   = blockIdx.x;
    const int grp   = bid >> 4;
    const int jc    = bid & 15;
    const int m0    = grp * 16;
    const int j0    = jc * 32;
    const int n0    = jc * 16;

    // per-group flag region: 2048 ints (8 KB)
    //   hfl: 64 flags (16 blocks x 4 epilogue waves) at [i*16]
    //   xfl: 16 flags (x' producer wave of each block) at [1024 + i*16]
    int* gfl = P.flags + grp * 2048;
    int* hfl = gfl;
    int* xfl = gfl + 1024;

    __shared__ unsigned short sh_h[16 * 512];
    __shared__ unsigned short sh_xp[16 * 256];
    __shared__ float sh_gh[16 * GHP];
    __shared__ float sh_gx[2][16 * GHP];
    __shared__ float sh_hf[16 * 32];
    __shared__ float sh_b[6][32];
    __shared__ float sh_bt[16];

    if (tid < 32) {
        sh_b[0][tid] = P.bih[j0 + tid];
        sh_b[1][tid] = P.bih[512 + j0 + tid];
        sh_b[2][tid] = P.bih[1024 + j0 + tid];
        sh_b[3][tid] = P.bhh[j0 + tid];
        sh_b[4][tid] = P.bhh[512 + j0 + tid];
        sh_b[5][tid] = P.bhh[1024 + j0 + tid];
    }
    if (tid < 16) sh_bt[tid] = P.bt[n0 + tid];
    sh_hf[tid] = 0.f; sh_hf[tid + 256] = 0.f;

    // ---- hoist step-invariant MFMA B-operands into registers (r7-proven shape) ----
    short8 bWih[3][4];
    short8 bWhh[2][16];
    #pragma unroll
    for (int i = 0; i < 3; ++i) {
        const int u = w * 3 + i, tile = u >> 1, kh = u & 1;
        const int g = tile >> 1, sub = tile & 1;
        const unsigned short* bp =
            P.Wihb + (size_t)(g * 512 + j0 + sub * 16 + lr) * NXP + kh * 128 + lk;
        #pragma unroll
        for (int kb = 0; kb < 4; ++kb) bWih[i][kb] = *(const short8*)(bp + kb * 32);
    }
    if (w < 3) {
        #pragma unroll
        for (int sub = 0; sub < 2; ++sub) {
            const unsigned short* bp =
                P.Whhb + (size_t)(w * 512 + j0 + sub * 16 + lr) * NH + lk;
            #pragma unroll
            for (int kb = 0; kb < 16; ++kb) bWhh[sub][kb] = *(const short8*)(bp + kb * 32);
        }
    } else {
        const unsigned short* bp = P.Wthb + (size_t)(n0 + lr) * NH + lk;
        #pragma unroll
        for (int kb = 0; kb < 16; ++kb) bWhh[0][kb] = *(const short8*)(bp + kb * 32);
        const unsigned short* bx = P.Wtxb + (size_t)(n0 + lr) * 160 + lk;
        #pragma unroll
        for (int c = 0; c < 5; ++c) bWhh[1][c] = *(const short8*)(bx + c * 32);
    }
    __syncthreads();

    for (int t = 0; t < NT; ++t) {
        const unsigned short* hsrc = (t & 1) ? P.hb1 : P.hb0;
        unsigned short*       hdst = (t & 1) ? P.hb0 : P.hb1;

        // x-input loads early (plain cached; overlaps the h-poll)
        float4 xq[5][2];
        if (w == 3) {
            const size_t r = (size_t)(m0 + lr);
            #pragma unroll
            for (int c = 0; c < 5; ++c) {
                const float* pa = (c < 2) ? P.xl + (r * NT + t) * 64 + c * 32 + lk
                                : (c == 2)? P.xt + (r * NT + t) * 32 + lk
                                : (c == 3)? P.xw + (r * NT + t) * 32 + lk
                                          : P.xs + (r * NT + t) * 32 + lk;
                xq[c][0] = *(const float4*)pa;
                xq[c][1] = *(const float4*)(pa + 4);
            }
        }

        // ---- wait for h_t: ONLY wave 0 polls (64 lanes : 64 per-wave flags) ----
        if (w == 0) poll64(hfl, t, lane);
        __syncthreads();
        // stage h[16 x 512] -> LDS
        {
            const int row = tid >> 4, c = (tid & 15) * 32;
            const unsigned short* gp = hsrc + (size_t)(m0 + row) * NH + c;
            uintx4 r0, r1, r2, r3;
            ldg4_c(gp, gp + 8, gp + 16, gp + 24, r0, r1, r2, r3);
            const int sw = (row & 7) * 8;
            *(uintx4*)&sh_h[row * 512 + ((c +  0) ^ sw)] = r0;
            *(uintx4*)&sh_h[row * 512 + ((c +  8) ^ sw)] = r1;
            *(uintx4*)&sh_h[row * 512 + ((c + 16) ^ sw)] = r2;
            *(uintx4*)&sh_h[row * 512 + ((c + 24) ^ sw)] = r3;
        }
        __syncthreads();

        // ---- Phase A: gh (waves 0-2) / x' (wave 3) ----
        if (w < 3) {
            floatx4 a0 = (floatx4){0.f,0.f,0.f,0.f};
            floatx4 a1 = (floatx4){0.f,0.f,0.f,0.f};
            const int sw = (lr & 7) * 8;
            #pragma unroll
            for (int kb = 0; kb < 16; ++kb) {
                short8 a = *(const short8*)&sh_h[lr * 512 + ((kb * 32 + lk) ^ sw)];
                a0 = MFMA(a, bWhh[0][kb], a0, 0, 0, 0);
                a1 = MFMA(a, bWhh[1][kb], a1, 0, 0, 0);
            }
            #pragma unroll
            for (int rg = 0; rg < 4; ++rg) {
                const int row = lkrow * 4 + rg;
                sh_gh[row * GHP + w * 32 + lr]      = a0[rg];
                sh_gh[row * GHP + w * 32 + 16 + lr] = a1[rg];
            }
        } else {
            floatx4 acc = (floatx4){0.f,0.f,0.f,0.f};
            const int sw = (lr & 7) * 8;
            #pragma unroll
            for (int kb = 0; kb < 16; ++kb) {
                short8 a = *(const short8*)&sh_h[lr * 512 + ((kb * 32 + lk) ^ sw)];
                acc = MFMA(a, bWhh[0][kb], acc, 0, 0, 0);
            }
            #pragma unroll
            for (int c = 0; c < 5; ++c) {
                short8 a = cvt8(xq[c][0], xq[c][1]);
                acc = MFMA(a, bWhh[1][c], acc, 0, 0, 0);
            }
            #pragma unroll
            for (int rg = 0; rg < 4; ++rg) {
                const int row = lkrow * 4 + rg;
                unsigned short v = f2bf(tanhf(acc[rg] + sh_bt[lr]));
                st16_c(P.xpb + (size_t)(m0 + row) * NXP + n0 + lr, (unsigned)v);
            }
            vm_drain();
            if (lane == 0) flag_set(xfl + jc * 16, t + 1);
        }

        // ---- wait for x'_t: ONLY wave 0 polls (16 flags) ----
        if (w == 0) poll16(xfl, t + 1, lane);
        __syncthreads();
        // stage x'[16 x 256] -> LDS
        {
            const int row = tid >> 4, c = (tid & 15) * 16;
            const unsigned short* gp = P.xpb + (size_t)(m0 + row) * NXP + c;
            uintx4 r0, r1;
            ldg2_c(gp, gp + 8, r0, r1);
            const int sw = (row & 7) * 8;
            *(uintx4*)&sh_xp[row * 256 + ((c + 0) ^ sw)] = r0;
            *(uintx4*)&sh_xp[row * 256 + ((c + 8) ^ sw)] = r1;
        }
        __syncthreads();

        // ---- Phase B: gx ----
        #pragma unroll
        for (int i = 0; i < 3; ++i) {
            const int u = w * 3 + i, tile = u >> 1, kh = u & 1;
            const int g = tile >> 1, sub = tile & 1;
            floatx4 acc = (floatx4){0.f,0.f,0.f,0.f};
            const int sw = (lr & 7) * 8;
            #pragma unroll
            for (int kb = 0; kb < 4; ++kb) {
                short8 a = *(const short8*)&sh_xp[lr * 256 + ((kh * 128 + kb * 32 + lk) ^ sw)];
                acc = MFMA(a, bWih[i][kb], acc, 0, 0, 0);
            }
            #pragma unroll
            for (int rg = 0; rg < 4; ++rg) {
                const int row = lkrow * 4 + rg;
                sh_gx[kh][row * GHP + g * 32 + sub * 16 + lr] = acc[rg];
            }
        }
        __syncthreads();

        // ---- epilogue: gates + h update; PER-WAVE flag right after own drain ----
        {
            const int row = tid >> 4, jj = (tid & 15) * 2;
            float hn[2];
            #pragma unroll
            for (int jo = 0; jo < 2; ++jo) {
                const int j = jj + jo;
                float gxr = sh_gx[0][row * GHP + j]      + sh_gx[1][row * GHP + j];
                float gxz = sh_gx[0][row * GHP + 32 + j] + sh_gx[1][row * GHP + 32 + j];
                float gxn = sh_gx[0][row * GHP + 64 + j] + sh_gx[1][row * GHP + 64 + j];
                float ghr = sh_gh[row * GHP + j];
                float ghz = sh_gh[row * GHP + 32 + j];
                float ghn = sh_gh[row * GHP + 64 + j];
                float rg_ = sigmoidf_(gxr + ghr + sh_b[0][j] + sh_b[3][j]);
                float zg  = sigmoidf_(gxz + ghz + sh_b[1][j] + sh_b[4][j]);
                float ng  = tanhf(gxn + sh_b[2][j] + rg_ * (ghn + sh_b[5][j]));
                float hold = sh_hf[row * 32 + j];
                hn[jo] = (1.f - zg) * ng + zg * hold;
                sh_hf[row * 32 + j] = hn[jo];
            }
            unsigned d = (unsigned)f2bf(hn[0]) | ((unsigned)f2bf(hn[1]) << 16);
            st32_c(hdst + (size_t)(m0 + row) * NH + j0 + jj, d);
            if (t == NT - 1) {
                float2 o; o.x = hn[0]; o.y = hn[1];
                *(float2*)&P.out[(size_t)(m0 + row) * NH + j0 + jj] = o;
            }
            vm_drain();   // wave-level: covers all 64 lanes' stores of this wave
            if (lane == 0) flag_set(hfl + (jc * 4 + w) * 16, t + 1);
        }
        // no trailing __syncthreads: next-iteration barriers order LDS reuse
    }
}

extern "C" void kernel_launch(void* const* d_in, const int* in_sizes, int n_in,
                              void* d_out, int out_size, void* d_ws, size_t ws_size,
                              hipStream_t stream)
{
    (void)in_sizes; (void)n_in; (void)out_size;
    const float* xl  = (const float*)d_in[0];
    const float* xt_ = (const float*)d_in[1];
    const float* xw  = (const float*)d_in[2];
    const float* xs  = (const float*)d_in[3];
    const float* Wih = (const float*)d_in[4];
    const float* Whh = (const float*)d_in[5];
    const float* bih = (const float*)d_in[6];
    const float* bhh = (const float*)d_in[7];
    const float* Wth = (const float*)d_in[8];
    const float* Wtx = (const float*)d_in[9];
    const float* bt  = (const float*)d_in[10];

    char* p = (char*)d_ws;
    int* flags = (int*)p;                       p += 16 * 2048 * 4;   // 131072 B
    unsigned short* hb0 = (unsigned short*)p;   p += (size_t)NB * NH * 2;
    unsigned short* hb1 = (unsigned short*)p;   p += (size_t)NB * NH * 2;
    unsigned short* xpb = (unsigned short*)p;   p += (size_t)NB * NXP * 2;
    unsigned short* Wihb = (unsigned short*)p;  p += (size_t)1536 * 256 * 2;
    unsigned short* Whhb = (unsigned short*)p;  p += (size_t)1536 * 512 * 2;
    unsigned short* Wthb = (unsigned short*)p;  p += (size_t)256 * 512 * 2;
    unsigned short* Wtxb = (unsigned short*)p;  p += (size_t)256 * 160 * 2;
    if ((size_t)(p - (char*)d_ws) > ws_size) return;

    k_cvt<<<256, 256, 0, stream>>>(Wih, Wihb, 1536 * 256);
    k_cvt<<<256, 256, 0, stream>>>(Whh, Whhb, 1536 * 512);
    k_cvt<<<64, 256, 0, stream>>>(Wth, Wthb, 256 * 512);
    k_cvt<<<32, 256, 0, stream>>>(Wtx, Wtxb, 256 * 160);
    hipMemsetAsync(flags, 0, 16 * 2048 * 4, stream);
    hipMemsetAsync(hb0, 0, (size_t)NB * NH * 2, stream);

    KParams P;
    P.xl = xl; P.xt = xt_; P.xw = xw; P.xs = xs;
    P.bih = bih; P.bhh = bhh; P.bt = bt;
    P.Wihb = Wihb; P.Whhb = Whhb; P.Wthb = Wthb; P.Wtxb = Wtxb;
    P.hb0 = hb0; P.hb1 = hb1; P.xpb = xpb;
    P.out = (float*)d_out; P.flags = flags;

    void* args[] = { &P };
    if (hipLaunchCooperativeKernel((const void*)k_persist, dim3(256), dim3(256),
                                   args, 0, stream) != hipSuccess) {
        k_persist<<<256, 256, 0, stream>>>(P);
    }
}